// Round 2
// baseline (246.731 us; speedup 1.0000x reference)
//
#include <hip/hip_runtime.h>
#include <math.h>

// Problem constants
#define NB 4
#define TT 256
#define DMODEL 1024
#define NE 16
#define DLQ 64
#define NH 4
#define HD 16
#define SEQL 17
#define NTOK 1024   // NB*TT

// Workspace layout (float offsets). Total footprint kept <= Round-1's proven
// 16.9 MB (XPART region is reused for PR/TW/TI after k_global_ctx consumes it).
static constexpr size_t WS_EF    = 0;                          // 1024x1024 fp32 ef
static constexpr size_t WS_A     = 1048576;                    // A' bf16 1024x3072 (as 1.5M floats)
static constexpr size_t WS_B     = 2621440;                    // B' bf16 1024x3072
static constexpr size_t WS_XPART = 4194304;                    // 32x1024 batch partials (early)
static constexpr size_t WS_PR    = 4194304;                    // 1024x16 probs (late, overlays XPART)
static constexpr size_t WS_TW    = 4210688;                    // 1024x2 top-k weights
static constexpr size_t WS_TI    = 4212736;                    // 1024x2 top-k indices (int)
static constexpr size_t WS_GCTX  = 4227072;                    // 4x64
static constexpr size_t WS_GB    = 4227328;                    // 4x16

typedef __attribute__((ext_vector_type(8))) short short8;
typedef __attribute__((ext_vector_type(4))) float f32x4;

__device__ __forceinline__ float gelu_exact(float x) {
    return 0.5f * x * (1.0f + erff(x * 0.70710678118654752f));
}

// bf16 round-to-nearest-even (inputs are normal floats, no NaN handling needed)
__device__ __forceinline__ unsigned short f2bf(float f) {
    unsigned int u = __float_as_uint(f);
    unsigned int r = (u + 0x7fffu + ((u >> 16) & 1u)) >> 16;
    return (unsigned short)r;
}
__device__ __forceinline__ float bf2f(unsigned short h) {
    return __uint_as_float(((unsigned int)h) << 16);
}

#define WSUM(v) { v += __shfl_xor(v,1); v += __shfl_xor(v,2); v += __shfl_xor(v,4); \
                  v += __shfl_xor(v,8); v += __shfl_xor(v,16); v += __shfl_xor(v,32); }

// K0: build split-bf16 operands. A' row = [xh | xl | xh], B' row = [wh | wh | wl]
// so A'.B'^T over K=3072 = xh.wh + xl.wh + xh.wl  (~fp32-accurate).
__global__ __launch_bounds__(256) void k_prep(const float* __restrict__ x,
                                              const float* __restrict__ wdn,
                                              float* __restrict__ ws) {
    int row = blockIdx.x, t = threadIdx.x;
    const float* src = blockIdx.y ? wdn : x;
    unsigned short* dst = (unsigned short*)(ws + (blockIdx.y ? WS_B : WS_A)) + (size_t)row * 3072;
    float4 v = *(const float4*)(src + (size_t)row * DMODEL + t * 4);
    ushort4 hi4, lo4;
    hi4.x = f2bf(v.x); lo4.x = f2bf(v.x - bf2f(hi4.x));
    hi4.y = f2bf(v.y); lo4.y = f2bf(v.y - bf2f(hi4.y));
    hi4.z = f2bf(v.z); lo4.z = f2bf(v.z - bf2f(hi4.z));
    hi4.w = f2bf(v.w); lo4.w = f2bf(v.w - bf2f(hi4.w));
    if (blockIdx.y == 0) {
        *(ushort4*)(dst + t * 4)        = hi4;
        *(ushort4*)(dst + 1024 + t * 4) = lo4;
        *(ushort4*)(dst + 2048 + t * 4) = hi4;
    } else {
        *(ushort4*)(dst + t * 4)        = hi4;
        *(ushort4*)(dst + 1024 + t * 4) = hi4;
        *(ushort4*)(dst + 2048 + t * 4) = lo4;
    }
}

// K1a: per-(batch, slice) column sums of x
__global__ __launch_bounds__(256) void k_batch_partial(const float* __restrict__ x,
                                                       float* __restrict__ ws) {
    int b = blockIdx.x >> 3;
    int g = blockIdx.x & 7;
    int tid = threadIdx.x;
    const float* xp = x + (size_t)b * TT * DMODEL + (size_t)g * 32 * DMODEL + tid * 4;
    float4 acc = {0.f, 0.f, 0.f, 0.f};
#pragma unroll 4
    for (int t = 0; t < 32; ++t) {
        float4 v = *(const float4*)(xp + (size_t)t * DMODEL);
        acc.x += v.x; acc.y += v.y; acc.z += v.z; acc.w += v.w;
    }
    *(float4*)(ws + WS_XPART + (size_t)blockIdx.x * DMODEL + tid * 4) = acc;
}

// K1b: per batch: xmean -> gctx -> gelu MLP -> gb
__global__ __launch_bounds__(256) void k_global_ctx(const float* __restrict__ gp_w,
                                                    const float* __restrict__ gp_b,
                                                    const float* __restrict__ g1_w,
                                                    const float* __restrict__ g1_b,
                                                    const float* __restrict__ g2_w,
                                                    const float* __restrict__ g2_b,
                                                    float* __restrict__ ws) {
    int b = blockIdx.x, tid = threadIdx.x;
    __shared__ float xm[DMODEL];
    __shared__ float gc[DLQ];
    __shared__ float gb1[128];
    float4 a = {0.f, 0.f, 0.f, 0.f};
#pragma unroll
    for (int g = 0; g < 8; ++g) {
        float4 v = *(const float4*)(ws + WS_XPART + (size_t)(b * 8 + g) * DMODEL + tid * 4);
        a.x += v.x; a.y += v.y; a.z += v.z; a.w += v.w;
    }
    const float inv_t = 1.0f / (float)TT;
    xm[tid * 4 + 0] = a.x * inv_t;
    xm[tid * 4 + 1] = a.y * inv_t;
    xm[tid * 4 + 2] = a.z * inv_t;
    xm[tid * 4 + 3] = a.w * inv_t;
    __syncthreads();
    if (tid < DLQ) {
        const float* wr = gp_w + (size_t)tid * DMODEL;
        float s = 0.f;
        for (int j = 0; j < DMODEL; j += 4) {
            float4 w4 = *(const float4*)(wr + j);
            float4 x4 = *(const float4*)&xm[j];
            s += w4.x * x4.x + w4.y * x4.y + w4.z * x4.z + w4.w * x4.w;
        }
        float v = s + gp_b[tid];
        gc[tid] = v;
        ws[WS_GCTX + b * DLQ + tid] = v;
    }
    __syncthreads();
    if (tid < 128) {
        const float* wr = g1_w + (size_t)tid * DLQ;
        float s = 0.f;
        for (int j = 0; j < DLQ; j += 4) {
            float4 w4 = *(const float4*)(wr + j);
            float4 x4 = *(const float4*)&gc[j];
            s += w4.x * x4.x + w4.y * x4.y + w4.z * x4.z + w4.w * x4.w;
        }
        gb1[tid] = gelu_exact(s + g1_b[tid]);
    }
    __syncthreads();
    if (tid < NE) {
        const float* wr = g2_w + (size_t)tid * 128;
        float s = 0.f;
        for (int j = 0; j < 128; ++j) s += wr[j] * gb1[j];
        ws[WS_GB + b * NE + tid] = s + g2_b[tid];
    }
}

// K2: ef = A' . B'^T via bf16 MFMA, K=3072, 64x64 tile, global_load_lds staging.
__global__ __launch_bounds__(256) void k_ef_mfma(float* __restrict__ ws) {
    __shared__ __attribute__((aligned(16))) unsigned short As[64 * 64];
    __shared__ __attribute__((aligned(16))) unsigned short Bs[64 * 64];
    const unsigned short* A = (const unsigned short*)(ws + WS_A);
    const unsigned short* B = (const unsigned short*)(ws + WS_B);
    int tid = threadIdx.x;
    int m0 = blockIdx.x * 64;
    int n0 = blockIdx.y * 64;
    int lr = tid >> 3;          // staging row 0..31
    int lc = (tid & 7) * 8;     // staging col (bf16 units; 16B chunks)
    const unsigned short* gA = A + (size_t)(n0 + lr) * 3072 + lc;
    const unsigned short* gB = B + (size_t)(m0 + lr) * 3072 + lc;

    int w = tid >> 6, l = tid & 63;
    int wn = (w >> 1) * 32, wm = (w & 1) * 32;
    int fr = l & 15;            // fragment row
    int fk = (l >> 4) * 8;      // fragment k offset
    f32x4 acc00 = {0.f, 0.f, 0.f, 0.f}, acc01 = acc00, acc10 = acc00, acc11 = acc00;

    for (int kt = 0; kt < 48; ++kt) {
        __builtin_amdgcn_global_load_lds(
            (const __attribute__((address_space(1))) void*)(gA),
            (__attribute__((address_space(3))) void*)((char*)As + tid * 16), 16, 0, 0);
        __builtin_amdgcn_global_load_lds(
            (const __attribute__((address_space(1))) void*)(gA + 32 * 3072),
            (__attribute__((address_space(3))) void*)((char*)As + 4096 + tid * 16), 16, 0, 0);
        __builtin_amdgcn_global_load_lds(
            (const __attribute__((address_space(1))) void*)(gB),
            (__attribute__((address_space(3))) void*)((char*)Bs + tid * 16), 16, 0, 0);
        __builtin_amdgcn_global_load_lds(
            (const __attribute__((address_space(1))) void*)(gB + 32 * 3072),
            (__attribute__((address_space(3))) void*)((char*)Bs + 4096 + tid * 16), 16, 0, 0);
        gA += 64; gB += 64;
        __syncthreads();
#pragma unroll
        for (int ks = 0; ks < 64; ks += 32) {
            short8 a0 = *(const short8*)&As[(wn + fr) * 64 + fk + ks];
            short8 a1 = *(const short8*)&As[(wn + 16 + fr) * 64 + fk + ks];
            short8 b0 = *(const short8*)&Bs[(wm + fr) * 64 + fk + ks];
            short8 b1 = *(const short8*)&Bs[(wm + 16 + fr) * 64 + fk + ks];
            acc00 = __builtin_amdgcn_mfma_f32_16x16x32_bf16(a0, b0, acc00, 0, 0, 0);
            acc01 = __builtin_amdgcn_mfma_f32_16x16x32_bf16(a0, b1, acc01, 0, 0, 0);
            acc10 = __builtin_amdgcn_mfma_f32_16x16x32_bf16(a1, b0, acc10, 0, 0, 0);
            acc11 = __builtin_amdgcn_mfma_f32_16x16x32_bf16(a1, b1, acc11, 0, 0, 0);
        }
        __syncthreads();
    }
    // C/D layout: col = lane&15, row = (lane>>4)*4 + reg
    int cr = (l >> 4) * 4, cc = l & 15;
    float* efb = ws + WS_EF;
#pragma unroll
    for (int r = 0; r < 4; ++r) {
        efb[(size_t)(n0 + wn + cr + r) * DMODEL + (m0 + wm + cc)]           = acc00[r];
        efb[(size_t)(n0 + wn + cr + r) * DMODEL + (m0 + wm + 16 + cc)]      = acc01[r];
        efb[(size_t)(n0 + wn + 16 + cr + r) * DMODEL + (m0 + wm + cc)]      = acc10[r];
        efb[(size_t)(n0 + wn + 16 + cr + r) * DMODEL + (m0 + wm + 16 + cc)] = acc11[r];
    }
}

// K3: wave-per-token attention + routing. 2 tokens/block, 128 threads.
__global__ __launch_bounds__(128) void k_attn(const float* __restrict__ pos_embed,
                                              const float* __restrict__ attn_in_w,
                                              const float* __restrict__ attn_in_b,
                                              const float* __restrict__ attn_out_w,
                                              const float* __restrict__ attn_out_b,
                                              const float* __restrict__ ln_w,
                                              const float* __restrict__ ln_b,
                                              const float* __restrict__ ls_w,
                                              const float* __restrict__ ls_b,
                                              float* __restrict__ ws) {
    int w = threadIdx.x >> 6;
    int l = threadIdx.x & 63;
    int n = blockIdx.x * 2 + w;
    int b = n >> 8;

    __shared__ float seq[2][SEQL][DLQ];
    __shared__ float qq[2][SEQL][DLQ];
    __shared__ float kk[2][SEQL][DLQ];
    __shared__ float vv[2][SEQL][DLQ];
    __shared__ float att[2][NH][SEQL][SEQL];
    __shared__ float ctx[2][SEQL][DLQ];

    const float* efp = ws + WS_EF + (size_t)n * DMODEL;

    // seq = [gctx ; ef + pos]
    seq[w][0][l] = ws[WS_GCTX + b * DLQ + l];
#pragma unroll
    for (int i = 0; i < NE; ++i)
        seq[w][1 + i][l] = efp[i * DLQ + l] + pos_embed[i * DLQ + l];
    __syncthreads();

    // qkv: 3 output columns per lane (o = l, 64+l, 128+l)
    {
        float aq[SEQL], ak[SEQL], av[SEQL];
#pragma unroll
        for (int i = 0; i < SEQL; ++i) { aq[i] = 0.f; ak[i] = 0.f; av[i] = 0.f; }
        const float* wq = attn_in_w + (size_t)l * DLQ;
        const float* wk = attn_in_w + (size_t)(64 + l) * DLQ;
        const float* wv = attn_in_w + (size_t)(128 + l) * DLQ;
        for (int j0 = 0; j0 < DLQ; j0 += 4) {
            float4 q4 = *(const float4*)(wq + j0);
            float4 k4 = *(const float4*)(wk + j0);
            float4 v4 = *(const float4*)(wv + j0);
#pragma unroll
            for (int i = 0; i < SEQL; ++i) {
                float4 s4 = *(const float4*)&seq[w][i][j0];
                aq[i] += s4.x * q4.x + s4.y * q4.y + s4.z * q4.z + s4.w * q4.w;
                ak[i] += s4.x * k4.x + s4.y * k4.y + s4.z * k4.z + s4.w * k4.w;
                av[i] += s4.x * v4.x + s4.y * v4.y + s4.z * v4.z + s4.w * v4.w;
            }
        }
        float bq = attn_in_b[l], bk = attn_in_b[64 + l], bv = attn_in_b[128 + l];
#pragma unroll
        for (int i = 0; i < SEQL; ++i) {
            qq[w][i][l] = aq[i] + bq;
            kk[w][i][l] = ak[i] + bk;
            vv[w][i][l] = av[i] + bv;
        }
    }
    __syncthreads();

    // scores: 4*17*17 = 1156 entries, strided over 64 lanes
    for (int idx = l; idx < NH * SEQL * SEQL; idx += 64) {
        int h = idx / (SEQL * SEQL);
        int r = idx - h * SEQL * SEQL;
        int i = r / SEQL, j = r - i * SEQL;
        float s = 0.f;
#pragma unroll
        for (int d = 0; d < HD; ++d) s += qq[w][i][h * HD + d] * kk[w][j][h * HD + d];
        att[w][h][i][j] = s * 0.25f;
    }
    __syncthreads();

    // softmax: 68 rows over 64 lanes
    for (int row = l; row < NH * SEQL; row += 64) {
        int h = row / SEQL, i = row - h * SEQL;
        float m = -1e30f;
#pragma unroll
        for (int j = 0; j < SEQL; ++j) m = fmaxf(m, att[w][h][i][j]);
        float ssum = 0.f;
#pragma unroll
        for (int j = 0; j < SEQL; ++j) {
            float e = expf(att[w][h][i][j] - m);
            att[w][h][i][j] = e;
            ssum += e;
        }
        float inv = 1.f / ssum;
#pragma unroll
        for (int j = 0; j < SEQL; ++j) att[w][h][i][j] *= inv;
    }
    __syncthreads();

    // ctx: lane l owns column l; h = l>>4
    {
        float c[SEQL];
#pragma unroll
        for (int i = 0; i < SEQL; ++i) c[i] = 0.f;
        int h = l >> 4;
#pragma unroll
        for (int j = 0; j < SEQL; ++j) {
            float vj = vv[w][j][l];
#pragma unroll
            for (int i = 0; i < SEQL; ++i) c[i] += att[w][h][i][j] * vj;
        }
#pragma unroll
        for (int i = 0; i < SEQL; ++i) ctx[w][i][l] = c[i];
    }
    __syncthreads();

    // attn_out + residual -> rs[i] held in registers (column l)
    float rs[SEQL];
    {
        const float* wo = attn_out_w + (size_t)l * DLQ;
        float a[SEQL];
#pragma unroll
        for (int i = 0; i < SEQL; ++i) a[i] = 0.f;
        for (int j0 = 0; j0 < DLQ; j0 += 4) {
            float4 w4 = *(const float4*)(wo + j0);
#pragma unroll
            for (int i = 0; i < SEQL; ++i) {
                float4 c4 = *(const float4*)&ctx[w][i][j0];
                a[i] += c4.x * w4.x + c4.y * w4.y + c4.z * w4.z + c4.w * w4.w;
            }
        }
        float bo = attn_out_b[l];
#pragma unroll
        for (int i = 0; i < SEQL; ++i) rs[i] = seq[w][i][l] + a[i] + bo;
    }

    // LN + logits via butterfly reductions; every lane computes all 16 logits.
    float c1 = ln_w[l] * ls_w[l];
    float c1sum = c1;        WSUM(c1sum);
    float c0 = ln_b[l] * ls_w[l];
    float c0sum = c0;        WSUM(c0sum);
    float lsb0 = ls_b[0];
    float p[NE];
    {
        float lgv[NE];
#pragma unroll
        for (int e = 0; e < NE; ++e) {
            float x = rs[e + 1];
            float s1 = x, s2 = x * x, s3 = x * c1;
            WSUM(s1); WSUM(s2); WSUM(s3);
            float mu = s1 * (1.0f / DLQ);
            float var = s2 * (1.0f / DLQ) - mu * mu;
            float rstd = rsqrtf(var + 1e-5f);
            lgv[e] = rstd * (s3 - mu * c1sum) + c0sum + lsb0 + ws[WS_GB + b * NE + e];
        }
        float m = lgv[0];
#pragma unroll
        for (int e = 1; e < NE; ++e) m = fmaxf(m, lgv[e]);
        float ssum = 0.f;
#pragma unroll
        for (int e = 0; e < NE; ++e) { p[e] = expf(lgv[e] - m); ssum += p[e]; }
        float inv = 1.f / ssum;
#pragma unroll
        for (int e = 0; e < NE; ++e) p[e] *= inv;
    }
    // top-2 (tie -> lower index)
    int t0 = 0; float b0 = p[0];
#pragma unroll
    for (int e = 1; e < NE; ++e) if (p[e] > b0) { b0 = p[e]; t0 = e; }
    int t1 = -1; float b1 = -1.f;
#pragma unroll
    for (int e = 0; e < NE; ++e) if (e != t0 && p[e] > b1) { b1 = p[e]; t1 = e; }

    if (l == 0) {
        float sw = b0 + b1;
        ws[WS_TW + n * 2 + 0] = b0 / sw;
        ws[WS_TW + n * 2 + 1] = b1 / sw;
        int* ti = (int*)(ws + WS_TI);
        ti[n * 2 + 0] = t0;
        ti[n * 2 + 1] = t1;
#pragma unroll
        for (int e = 0; e < NE; ++e) ws[WS_PR + (size_t)n * NE + e] = p[e];
    }
}

// K4: expert-up mixing. One block per token, barrier-light streaming from L2.
__global__ __launch_bounds__(256) void k_moe(const float* __restrict__ w_up,
                                             const float* __restrict__ ws,
                                             float* __restrict__ out) {
    int n = blockIdx.x, tid = threadIdx.x;
    __shared__ float acts[2 * DLQ];
    __shared__ int eidx[2];
    if (tid < 2) eidx[tid] = ((const int*)(ws + WS_TI))[n * 2 + tid];
    __syncthreads();
    if (tid < 2 * DLQ) {
        int k = tid >> 6, j = tid & 63;
        float tw = ws[WS_TW + n * 2 + k];
        acts[tid] = gelu_exact(ws[WS_EF + (size_t)n * DMODEL + eidx[k] * DLQ + j]) * tw;
    }
    __syncthreads();
    int col = tid * 4;
    const float* wb0 = w_up + (size_t)eidx[0] * DLQ * DMODEL + col;
    const float* wb1 = w_up + (size_t)eidx[1] * DLQ * DMODEL + col;
    float4 acc = {0.f, 0.f, 0.f, 0.f};
#pragma unroll 4
    for (int j = 0; j < DLQ; ++j) {
        float a0 = acts[j], a1 = acts[64 + j];
        float4 w0 = *(const float4*)(wb0 + (size_t)j * DMODEL);
        float4 w1 = *(const float4*)(wb1 + (size_t)j * DMODEL);
        acc.x += a0 * w0.x + a1 * w1.x;
        acc.y += a0 * w0.y + a1 * w1.y;
        acc.z += a0 * w0.z + a1 * w1.z;
        acc.w += a0 * w0.w + a1 * w1.w;
    }
    *(float4*)(out + (size_t)n * DMODEL + col) = acc;
}

// K5: aux loss from probs + top-k indices
__global__ __launch_bounds__(256) void k_aux(const float* __restrict__ ws, float* __restrict__ out) {
    int tid = threadIdx.x;
    __shared__ float sp[NE];
    __shared__ float scf[NE];
    if (tid < NE) { sp[tid] = 0.f; scf[tid] = 0.f; }
    __syncthreads();
    {   // probs column sums: thread (e = tid&15, chunk = tid>>4) over 64 rows
        int e = tid & 15, c = tid >> 4;
        float s = 0.f;
        for (int r = c * 64; r < c * 64 + 64; ++r) s += ws[WS_PR + (size_t)r * NE + e];
        atomicAdd(&sp[e], s);
    }
    {   // selection counts
        const int* ti = (const int*)(ws + WS_TI);
        for (int k = 0; k < 8; ++k) atomicAdd(&scf[ti[tid * 8 + k]], 1.0f);
    }
    __syncthreads();
    if (tid == 0) {
        float s = 0.f;
#pragma unroll
        for (int e = 0; e < NE; ++e) s += sp[e] * scf[e];
        out[(size_t)NTOK * DMODEL] = (float)NE * s / ((float)NTOK * (float)NTOK);
    }
}

extern "C" void kernel_launch(void* const* d_in, const int* in_sizes, int n_in,
                              void* d_out, int out_size, void* d_ws, size_t ws_size,
                              hipStream_t stream) {
    const float* x          = (const float*)d_in[0];
    const float* w_down     = (const float*)d_in[1];
    const float* pos_embed  = (const float*)d_in[2];
    const float* gp_w       = (const float*)d_in[3];
    const float* gp_b       = (const float*)d_in[4];
    const float* attn_in_w  = (const float*)d_in[5];
    const float* attn_in_b  = (const float*)d_in[6];
    const float* attn_out_w = (const float*)d_in[7];
    const float* attn_out_b = (const float*)d_in[8];
    const float* ln_w       = (const float*)d_in[9];
    const float* ln_b       = (const float*)d_in[10];
    const float* ls_w       = (const float*)d_in[11];
    const float* ls_b       = (const float*)d_in[12];
    const float* g1_w       = (const float*)d_in[13];
    const float* g1_b       = (const float*)d_in[14];
    const float* g2_w       = (const float*)d_in[15];
    const float* g2_b       = (const float*)d_in[16];
    const float* w_up       = (const float*)d_in[17];
    float* ws  = (float*)d_ws;
    float* out = (float*)d_out;

    k_prep<<<dim3(1024, 2), 256, 0, stream>>>(x, w_down, ws);
    k_batch_partial<<<32, 256, 0, stream>>>(x, ws);
    k_global_ctx<<<NB, 256, 0, stream>>>(gp_w, gp_b, g1_w, g1_b, g2_w, g2_b, ws);
    k_ef_mfma<<<dim3(16, 16), 256, 0, stream>>>(ws);
    k_attn<<<512, 128, 0, stream>>>(pos_embed, attn_in_w, attn_in_b, attn_out_w, attn_out_b,
                                    ln_w, ln_b, ls_w, ls_b, ws);
    k_moe<<<NTOK, 256, 0, stream>>>(w_up, ws, out);
    k_aux<<<1, 256, 0, stream>>>(ws, out);
}